// Round 10
// baseline (365.542 us; speedup 1.0000x reference)
//
#include <hip/hip_runtime.h>
#include <hip/hip_bf16.h>
#include <math.h>

// Problem constants (fixed by the reference).
constexpr int Bb = 8;
constexpr int Cc = 256;
constexpr int Hh = 4;
constexpr int Nn = 2048;
constexpr int Mm = 2048;
constexpr size_t BCN = (size_t)Bb * Cc * Nn;   // 4,194,304 elements

typedef __attribute__((ext_vector_type(8))) short short8;
typedef __attribute__((ext_vector_type(4))) float f32x4;

// log2(e): exp(x) == exp2(x * LOG2E); folded into Wq/bq so softmax uses exp2f.
constexpr float QSCALE = 0.125f * 1.4426950408889634f;

__device__ __forceinline__ unsigned short bfu(float x) {
  __hip_bfloat16 b = __float2bfloat16(x);        // RNE
  return __builtin_bit_cast(unsigned short, b);
}

// ---------------------------------------------------------------------------
// Weight quantization: f32 -> bf16 (Wq scaled by QSCALE). One launch, 6 segs.
// ---------------------------------------------------------------------------
__global__ __launch_bounds__(256) void quantw_kernel(
    const float* __restrict__ s0, const float* __restrict__ s1,
    const float* __restrict__ s2, const float* __restrict__ s3,
    const float* __restrict__ s4, const float* __restrict__ s5,
    unsigned short* __restrict__ d0, unsigned short* __restrict__ d1,
    unsigned short* __restrict__ d2, unsigned short* __restrict__ d3,
    unsigned short* __restrict__ d4, unsigned short* __restrict__ d5)
{
  const int seg = blockIdx.y;
  const float* s; unsigned short* d; int cnt; float sc = 1.f;
  switch (seg) {
    case 0: s = s0; d = d0; cnt = 65536;  sc = QSCALE; break;
    case 1: s = s1; d = d1; cnt = 65536;  break;
    case 2: s = s2; d = d2; cnt = 65536;  break;
    case 3: s = s3; d = d3; cnt = 65536;  break;
    case 4: s = s4; d = d4; cnt = 262144; break;
    default: s = s5; d = d5; cnt = 131072; break;
  }
  for (int i = blockIdx.x * 256 + threadIdx.x; i < cnt / 4; i += 64 * 256) {
    float4 v = ((const float4*)s)[i];
    unsigned int lo = bfu(v.x * sc) | ((unsigned int)bfu(v.y * sc) << 16);
    unsigned int hi = bfu(v.z * sc) | ((unsigned int)bfu(v.w * sc) << 16);
    ((uint2*)d)[i] = make_uint2(lo, hi);
  }
}

// ---------------------------------------------------------------------------
// Transpose+quantize: desc [b][256][2048] f32 -> [b][2048][256] bf16.
// ---------------------------------------------------------------------------
__global__ __launch_bounds__(256) void trans_kernel(
    const float* __restrict__ S1, const float* __restrict__ S2,
    unsigned short* __restrict__ D1, unsigned short* __restrict__ D2)
{
  __shared__ float T[64][65];
  const int z = blockIdx.z, b = z & 7;
  const float* S = (z >> 3) ? S2 : S1;
  unsigned short* D = (z >> 3) ? D2 : D1;
  const int n0 = blockIdx.x * 64, c0 = blockIdx.y * 64;
  const int t = threadIdx.x, t4 = t >> 6, tl = t & 63;

  #pragma unroll
  for (int r = 0; r < 16; ++r) {
    int cl = r * 4 + t4;
    T[cl][tl] = S[((size_t)b * 256 + c0 + cl) * 2048 + n0 + tl];
  }
  __syncthreads();
  #pragma unroll
  for (int r = 0; r < 16; ++r) {
    int nl = r * 4 + t4;
    D[((size_t)b * 2048 + n0 + nl) * 256 + c0 + tl] = bfu(T[tl][nl]);
  }
}

// ---------------------------------------------------------------------------
// Barrier-free direct-load bf16 MFMA GEMM. Wave = 32n x 64o; block = 4 waves
// (128n x 64o); no LDS, no barriers. X is K-contiguous [b][n][K]; W [o][K]
// L1-broadcast across waves. Frag loads are 16B/lane contiguous.
// EPI: 0 = Q/K  bf16 [b*H+by][n][64], (acc+bias)*oscale... bias pre-scaled
//      1 = V    bf16 [b][o][m], (acc+bias)*weight_v[b][m]
//      2 = M    bf16 [b][n][256], +bias
//      3 = C1   bf16 [b][n][512], BN+ReLU
//      4 = C2   f32  [b][o][n], +bias+residual
// ---------------------------------------------------------------------------
template<int K1, int K2, int EPI>
__global__ __launch_bounds__(256) void gemm_kernel(
    const unsigned short* __restrict__ Wb,
    const unsigned short* __restrict__ X1, const unsigned short* __restrict__ X2,
    const float* __restrict__ bias,
    const float* __restrict__ p0, const float* __restrict__ p1,
    const float* __restrict__ p2, const float* __restrict__ p3,
    void* __restrict__ Yv, float oscale)
{
  constexpr int KT = K1 + K2;
  constexpr bool TRANS = (EPI == 0 || EPI == 2 || EPI == 3);
  const int t  = threadIdx.x;
  const int wv = t >> 6, l = t & 63;
  const int c  = l & 15, h4 = l >> 4;
  const int n0 = blockIdx.x * 128 + wv * 32;
  const int o0 = blockIdx.y * 64;
  const int b  = blockIdx.z;

  f32x4 acc[2][4] = {};

  #pragma unroll 4
  for (int kt = 0; kt < KT / 32; ++kt) {
    const int k0 = kt * 32 + h4 * 8;
    const unsigned short* xb; int xs;
    if constexpr (K2 == 0) {
      xb = X1 + ((size_t)b * 2048 + n0) * K1 + k0; xs = K1;
    } else {
      if (kt * 32 < K1) { xb = X1 + ((size_t)b * 2048 + n0) * K1 + k0; xs = K1; }
      else              { xb = X2 + ((size_t)b * 2048 + n0) * K2 + (k0 - K1); xs = K2; }
    }
    short8 xf[2], wf[4];
    #pragma unroll
    for (int j = 0; j < 2; ++j)
      xf[j] = *(const short8*)(xb + (size_t)(j * 16 + c) * xs);
    #pragma unroll
    for (int f = 0; f < 4; ++f)
      wf[f] = *(const short8*)(Wb + (size_t)(o0 + f * 16 + c) * KT + k0);
    __builtin_amdgcn_s_setprio(1);
    #pragma unroll
    for (int j = 0; j < 2; ++j)
      #pragma unroll
      for (int f = 0; f < 4; ++f) {
        if constexpr (TRANS)
          acc[j][f] = __builtin_amdgcn_mfma_f32_16x16x32_bf16(xf[j], wf[f], acc[j][f], 0, 0, 0);
        else
          acc[j][f] = __builtin_amdgcn_mfma_f32_16x16x32_bf16(wf[f], xf[j], acc[j][f], 0, 0, 0);
      }
    __builtin_amdgcn_s_setprio(0);
  }

  // TRANS:    D elem (j,f,r): n = n0+j*16+h4*4+r, o = o0+f*16+c
  // nonTRANS: D elem (j,f,r): o = o0+f*16+h4*4+r, m = n0+j*16+c
  if constexpr (EPI == 0) {             // Qt/Kt [b*H+by][n][64] bf16
    unsigned short* Y = (unsigned short*)Yv;
    const int by = blockIdx.y;          // head
    #pragma unroll
    for (int f = 0; f < 4; ++f) {
      float bb = bias[o0 + f * 16 + c] * oscale;
      #pragma unroll
      for (int j = 0; j < 2; ++j)
        #pragma unroll
        for (int r = 0; r < 4; ++r) {
          int n = n0 + j * 16 + h4 * 4 + r;
          Y[(((size_t)b * Hh + by) * 2048 + n) * 64 + f * 16 + c] = bfu(acc[j][f][r] + bb);
        }
    }
  } else if constexpr (EPI == 2) {      // MoutT [b][n][256] bf16
    unsigned short* Y = (unsigned short*)Yv;
    #pragma unroll
    for (int f = 0; f < 4; ++f) {
      int o = o0 + f * 16 + c;
      float bb = bias[o];
      #pragma unroll
      for (int j = 0; j < 2; ++j)
        #pragma unroll
        for (int r = 0; r < 4; ++r) {
          int n = n0 + j * 16 + h4 * 4 + r;
          Y[((size_t)b * 2048 + n) * 256 + o] = bfu(acc[j][f][r] + bb);
        }
    }
  } else if constexpr (EPI == 3) {      // HT [b][n][512] bf16, BN+ReLU
    unsigned short* Y = (unsigned short*)Yv;
    #pragma unroll
    for (int f = 0; f < 4; ++f) {
      int o = o0 + f * 16 + c;
      float bb  = bias[o];
      float inv = p0[o] / sqrtf(p3[o] + 1e-5f);
      float add = p1[o] - p2[o] * inv;
      #pragma unroll
      for (int j = 0; j < 2; ++j)
        #pragma unroll
        for (int r = 0; r < 4; ++r) {
          int n = n0 + j * 16 + h4 * 4 + r;
          float v = fmaxf((acc[j][f][r] + bb) * inv + add, 0.f);
          Y[((size_t)b * 2048 + n) * 512 + o] = bfu(v);
        }
    }
  } else if constexpr (EPI == 1) {      // Vb [b][o][m] bf16, *weight_v
    unsigned short* Y = (unsigned short*)Yv;
    #pragma unroll
    for (int j = 0; j < 2; ++j) {
      int m = n0 + j * 16 + c;
      float sc = p0[(size_t)b * 2048 + m];
      #pragma unroll
      for (int f = 0; f < 4; ++f)
        #pragma unroll
        for (int r = 0; r < 4; ++r) {
          int o = o0 + f * 16 + h4 * 4 + r;
          Y[((size_t)b * 256 + o) * 2048 + m] = bfu((acc[j][f][r] + bias[o]) * sc);
        }
    }
  } else {                              // out [b][o][n] f32, +bias+residual
    float* Y = (float*)Yv;
    #pragma unroll
    for (int j = 0; j < 2; ++j) {
      int n = n0 + j * 16 + c;
      #pragma unroll
      for (int f = 0; f < 4; ++f)
        #pragma unroll
        for (int r = 0; r < 4; ++r) {
          int o = o0 + f * 16 + h4 * 4 + r;
          size_t idx = ((size_t)b * 256 + o) * 2048 + n;
          Y[idx] = acc[j][f][r] + bias[o] + p0[idx];
        }
    }
  }
}

// ---------------------------------------------------------------------------
// MFMA flash attention. Swapped QK^T; per-wave swizzled P LDS; barrier-free.
// Round-8: exp2 domain (scale folded into Qt), defer-max (THR=8), setprio,
// m-loop unroll 2 for cross-iter load hoisting.
// ---------------------------------------------------------------------------
__global__ __launch_bounds__(256) void attn_mfma_kernel(
    const unsigned short* __restrict__ Qt, const unsigned short* __restrict__ Kt,
    const unsigned short* __restrict__ Vb, unsigned short* __restrict__ Ot)
{
  const int id  = blockIdx.x;
  const int xcd = id & 7;
  const int s8  = id >> 3;
  const int bh  = xcd + 8 * (s8 >> 4);
  const int nb  = s8 & 15;
  const int wv  = threadIdx.x >> 6;
  const int l   = threadIdx.x & 63;
  const int c   = l & 15;
  const int h   = l >> 4;
  const int n0  = nb * 128 + wv * 32;

  const unsigned short* Qw = Qt + ((size_t)bh * Nn + n0) * 64;
  const unsigned short* Kb = Kt + (size_t)bh * Mm * 64;
  const unsigned short* Vw = Vb + (size_t)bh * 64 * Mm;

  __shared__ unsigned short Pl[4][32 * 64];
  char* P = (char*)Pl[wv];

  short8 qf[2][2];
  #pragma unroll
  for (int j = 0; j < 2; ++j)
    #pragma unroll
    for (int ks = 0; ks < 2; ++ks)
      qf[j][ks] = *(const short8*)(Qw + ((size_t)(j*16 + c)) * 64 + ks*32 + h*8);

  f32x4 acc[4][2];
  #pragma unroll
  for (int d = 0; d < 4; ++d)
    #pragma unroll
    for (int j = 0; j < 2; ++j) acc[d][j] = (f32x4){0.f,0.f,0.f,0.f};
  float rowM[2] = {-1e30f, -1e30f};
  float rowL[2] = {0.f, 0.f};

  #pragma unroll 2
  for (int m0 = 0; m0 < Mm; m0 += 64) {
    short8 kf[4][2];
    #pragma unroll
    for (int g = 0; g < 4; ++g)
      #pragma unroll
      for (int ks = 0; ks < 2; ++ks)
        kf[g][ks] = *(const short8*)(Kb + ((size_t)(m0 + g*16 + c)) * 64 + ks*32 + h*8);

    f32x4 sc4[4][2];
    __builtin_amdgcn_s_setprio(1);
    #pragma unroll
    for (int g = 0; g < 4; ++g)
      #pragma unroll
      for (int j = 0; j < 2; ++j) {
        f32x4 z = (f32x4){0.f,0.f,0.f,0.f};
        z = __builtin_amdgcn_mfma_f32_16x16x32_bf16(kf[g][0], qf[j][0], z, 0, 0, 0);
        z = __builtin_amdgcn_mfma_f32_16x16x32_bf16(kf[g][1], qf[j][1], z, 0, 0, 0);
        sc4[g][j] = z;
      }
    __builtin_amdgcn_s_setprio(0);

    short8 vf[4][2];
    #pragma unroll
    for (int db = 0; db < 4; ++db)
      #pragma unroll
      for (int ks = 0; ks < 2; ++ks)
        vf[db][ks] = *(const short8*)(Vw + ((size_t)(db*16 + c)) * Mm + m0 + ks*32 + h*8);

    #pragma unroll
    for (int j = 0; j < 2; ++j) {
      float mx = -1e30f;
      #pragma unroll
      for (int g = 0; g < 4; ++g)
        #pragma unroll
        for (int r = 0; r < 4; ++r) mx = fmaxf(mx, sc4[g][j][r]);
      mx = fmaxf(mx, __shfl_xor(mx, 16));
      mx = fmaxf(mx, __shfl_xor(mx, 32));

      float sum = 0.f;
      if (__all(mx - rowM[j] <= 8.f)) {
        // defer-max: keep old m; P bounded by 2^8, no acc rescale.
        #pragma unroll
        for (int g = 0; g < 4; ++g)
          #pragma unroll
          for (int r = 0; r < 4; ++r) {
            float e = exp2f(sc4[g][j][r] - rowM[j]);
            sc4[g][j][r] = e;
            sum += e;
          }
        sum += __shfl_xor(sum, 16);
        sum += __shfl_xor(sum, 32);
        rowL[j] += sum;
      } else {
        float nm = fmaxf(rowM[j], mx);
        float corr = exp2f(rowM[j] - nm);
        rowM[j] = nm;
        #pragma unroll
        for (int g = 0; g < 4; ++g)
          #pragma unroll
          for (int r = 0; r < 4; ++r) {
            float e = exp2f(sc4[g][j][r] - nm);
            sc4[g][j][r] = e;
            sum += e;
          }
        sum += __shfl_xor(sum, 16);
        sum += __shfl_xor(sum, 32);
        rowL[j] = rowL[j] * corr + sum;
        #pragma unroll
        for (int db = 0; db < 4; ++db)
          #pragma unroll
          for (int r = 0; r < 4; ++r) acc[db][j][r] *= corr;
      }

      #pragma unroll
      for (int g = 0; g < 4; ++g) {
        unsigned int lo = ((unsigned int)bfu(sc4[g][j][1]) << 16) | bfu(sc4[g][j][0]);
        unsigned int hi = ((unsigned int)bfu(sc4[g][j][3]) << 16) | bfu(sc4[g][j][2]);
        int off = (j*16 + c) * 128 + g*32 + h*8;
        off ^= (c & 7) << 4;
        *(uint2*)(P + off) = make_uint2(lo, hi);
      }
    }

    #pragma unroll
    for (int j = 0; j < 2; ++j) {
      short8 pf[2];
      #pragma unroll
      for (int ks = 0; ks < 2; ++ks) {
        int off = (j*16 + c) * 128 + ks*64 + h*16;
        off ^= (c & 7) << 4;
        pf[ks] = *(const short8*)(P + off);
      }
      __builtin_amdgcn_s_setprio(1);
      #pragma unroll
      for (int db = 0; db < 4; ++db) {
        acc[db][j] = __builtin_amdgcn_mfma_f32_16x16x32_bf16(vf[db][0], pf[0], acc[db][j], 0, 0, 0);
        acc[db][j] = __builtin_amdgcn_mfma_f32_16x16x32_bf16(vf[db][1], pf[1], acc[db][j], 0, 0, 0);
      }
      __builtin_amdgcn_s_setprio(0);
    }
  }

  const float invl[2] = {1.f / rowL[0], 1.f / rowL[1]};
  unsigned short* Ob = Ot + ((size_t)(bh >> 2) * Nn) * 256 + (bh & 3) * 64;
  #pragma unroll
  for (int db = 0; db < 4; ++db)
    #pragma unroll
    for (int j = 0; j < 2; ++j) {
      unsigned int lo = ((unsigned int)bfu(acc[db][j][1] * invl[j]) << 16) | bfu(acc[db][j][0] * invl[j]);
      unsigned int hi = ((unsigned int)bfu(acc[db][j][3] * invl[j]) << 16) | bfu(acc[db][j][2] * invl[j]);
      *(uint2*)(Ob + (size_t)(n0 + j*16 + c) * 256 + db*16 + h*4) = make_uint2(lo, hi);
    }
}

// ---------------------------------------------------------------------------
extern "C" void kernel_launch(void* const* d_in, const int* in_sizes, int n_in,
                              void* d_out, int out_size, void* d_ws, size_t ws_size,
                              hipStream_t stream)
{
  (void)in_sizes; (void)n_in; (void)out_size; (void)ws_size;
  const float* desc1 = (const float*)d_in[0];
  const float* desc2 = (const float*)d_in[1];
  const float* wvv   = (const float*)d_in[2];
  const float* Wq  = (const float*)d_in[3];  const float* bq  = (const float*)d_in[4];
  const float* Wk  = (const float*)d_in[5];  const float* bk  = (const float*)d_in[6];
  const float* Wv  = (const float*)d_in[7];  const float* bv  = (const float*)d_in[8];
  const float* Wm  = (const float*)d_in[9];  const float* bm  = (const float*)d_in[10];
  const float* Wc1 = (const float*)d_in[11]; const float* bc1 = (const float*)d_in[12];
  const float* bng = (const float*)d_in[13]; const float* bnb = (const float*)d_in[14];
  const float* bnm = (const float*)d_in[15]; const float* bnv = (const float*)d_in[16];
  const float* Wc2 = (const float*)d_in[17]; const float* bc2 = (const float*)d_in[18];
  float* out = (float*)d_out;

  unsigned short* u = (unsigned short*)d_ws;
  unsigned short* D1t  = u;
  unsigned short* D2t  = u + BCN;
  unsigned short* Qt   = u + 2 * BCN;
  unsigned short* Kt   = u + 3 * BCN;
  unsigned short* Vbb  = u + 4 * BCN;
  unsigned short* Ot    = D2t;         // D2t dead after v-gemm
  unsigned short* MoutT = Qt;          // Qt dead after attn
  unsigned short* HT    = Kt;          // Kt+Vbb dead after attn (2*BCN)
  unsigned short* Wqb  = u + 5 * BCN;
  unsigned short* Wkb  = Wqb + 65536;
  unsigned short* Wvb  = Wkb + 65536;
  unsigned short* Wmb  = Wvb + 65536;
  unsigned short* Wc1b = Wmb + 65536;
  unsigned short* Wc2b = Wc1b + 262144;

  dim3 blk(256);
  quantw_kernel<<<dim3(64, 6), blk, 0, stream>>>(
      Wq, Wk, Wv, Wm, Wc1, Wc2, Wqb, Wkb, Wvb, Wmb, Wc1b, Wc2b);
  trans_kernel<<<dim3(32, 4, 16), blk, 0, stream>>>(desc1, desc2, D1t, D2t);

  // Qt = [bh][n][64] bf16 of QSCALE*(Wq desc1 + bq)   (exp2-domain scale)
  gemm_kernel<256,0,0><<<dim3(16, 4, Bb), blk, 0, stream>>>(
      Wqb, D1t, nullptr, bq, nullptr,nullptr,nullptr,nullptr, Qt, QSCALE);
  // Kt = [bh][m][64]
  gemm_kernel<256,0,0><<<dim3(16, 4, Bb), blk, 0, stream>>>(
      Wkb, D2t, nullptr, bk, nullptr,nullptr,nullptr,nullptr, Kt, 1.0f);
  // Vb = [b][o][m] * weight_v
  gemm_kernel<256,0,1><<<dim3(16, 4, Bb), blk, 0, stream>>>(
      Wvb, D2t, nullptr, bv, wvv,nullptr,nullptr,nullptr, Vbb, 1.0f);
  // attention -> Ot [b][n][256] bf16
  attn_mfma_kernel<<<dim3(512), blk, 0, stream>>>(Qt, Kt, Vbb, Ot);
  // MoutT = [b][n][256] bf16
  gemm_kernel<256,0,2><<<dim3(16, 4, Bb), blk, 0, stream>>>(
      Wmb, Ot, nullptr, bm, nullptr,nullptr,nullptr,nullptr, MoutT, 1.0f);
  // HT = [b][n][512] bf16 of relu(BN(Wc1 [desc1; mout] + bc1))
  gemm_kernel<256,256,3><<<dim3(16, 8, Bb), blk, 0, stream>>>(
      Wc1b, D1t, MoutT, bc1, bng,bnb,bnm,bnv, HT, 1.0f);
  // out = desc1 + Wc2 h + bc2  (f32)
  gemm_kernel<512,0,4><<<dim3(16, 4, Bb), blk, 0, stream>>>(
      Wc2b, HT, nullptr, bc2, desc1,nullptr,nullptr,nullptr, out, 1.0f);
}